// Round 3
// baseline (933.904 us; speedup 1.0000x reference)
//
#include <hip/hip_runtime.h>

// RNN scan: B=2048, T=512, V=64, H=256, K=H+V=320.
// R5: ONE barrier per step (was 2). Evidence: R2=R3=R4 wall time despite
// 1x/2x waves and 1x/2x blocks -> wall = 512 * chain latency; only chain
// cuts help. Changes:
//  - State stored RAW (pre-norm z, bf16). Normalize on READ: A-frag lane
//    owns row loc, and mean/rstd are lane-local (no broadcasts, no merge;
//    rstd factors out of the k-sum -> token MFMAs init the accumulator).
//  - Stats partials double-buffered; written pre-barrier, read post-barrier
//    lane-locally. The read latency hides under token MFMAs + prefetch.
//  - k-permutation sigma (16x16 transpose, self-inverse) applied to BOTH the
//    state LDS positions and the theta B-frag gather (dot product invariant):
//    makes each lane's 4 output values contiguous -> 4x ds_write_b64 raw-z
//    writes instead of 16x ds_write_b16.
//  - v_cvt_pk_bf16_f32 for all f32->bf16 packing.
// 128 blocks x 256 threads (4 waves), 16 real rows/block; theta resident in
// VGPRs (bfrag[10][4]); tokens prefetched 1 step ahead; s_barrier with
// lgkmcnt-only drain keeps prefetch in flight.

#define TT 512
#define VV 64
#define STRD 264   // ushorts per state row: 256 + 8 pad (528B, 16B-aligned rows)

typedef short bf16x8 __attribute__((ext_vector_type(8)));
typedef float f32x4  __attribute__((ext_vector_type(4)));

__device__ __forceinline__ unsigned int cvtpk(float lo, float hi) {
    unsigned int r;
    asm("v_cvt_pk_bf16_f32 %0, %1, %2" : "=v"(r) : "v"(lo), "v"(hi));
    return r;
}

__device__ __forceinline__ float bf2f(unsigned short u) {
    return __uint_as_float(((unsigned int)u) << 16);
}

__device__ __forceinline__ bf16x8 pack8(float4 a, float4 b) {
    union { unsigned int u[4]; bf16x8 v; } r;
    r.u[0] = cvtpk(a.x, a.y); r.u[1] = cvtpk(a.z, a.w);
    r.u[2] = cvtpk(b.x, b.y); r.u[3] = cvtpk(b.z, b.w);
    return r.v;
}

// raw bf16x8 frag (as 4 u32) -> normalized bf16x8: v = relu(z*a + b)
__device__ __forceinline__ bf16x8 normfrag(const unsigned int* rw, float a, float b) {
    union { unsigned int u[4]; bf16x8 v; } r;
#pragma unroll
    for (int i = 0; i < 4; ++i) {
        float lo = __uint_as_float(rw[i] << 16);
        float hi = __uint_as_float(rw[i] & 0xffff0000u);
        lo = fmaxf(fmaf(lo, a, b), 0.0f);
        hi = fmaxf(fmaf(hi, a, b), 0.0f);
        r.u[i] = cvtpk(lo, hi);
    }
    return r.v;
}

template <int CTRL>
__device__ __forceinline__ float dppadd(float x) {
    int y = __builtin_amdgcn_update_dpp(0, __float_as_int(x), CTRL, 0xF, 0xF, false);
    return x + __int_as_float(y);
}

// s_barrier with LDS-only drain (vmcnt stays in flight across it)
__device__ __forceinline__ void barrier_lgkm() {
    asm volatile("s_waitcnt lgkmcnt(0)\n\ts_barrier" ::: "memory");
}

extern "C" __global__ void __launch_bounds__(256, 1)
rnn_scan_kernel(const float* __restrict__ seq,        // [2048][512][64]
                const float* __restrict__ theta,      // [256][320]
                const float* __restrict__ theta_dot,  // [256]
                float* __restrict__ out)              // [2048]
{
    __shared__ unsigned short stbuf[2][16][STRD];           // RAW z, bf16, dbuf
    __shared__ __align__(16) float2 partials[2][16][4];     // [buf][row][wave] (sum, ssq)

    const int tid = threadIdx.x;
    const int w   = tid >> 6;        // wave 0..3 -> N columns [64w, 64w+64)
    const int l   = tid & 63;
    const int q   = l >> 4;          // k-octet / quad-row group 0..3
    const int loc = l & 15;
    const int r0  = blockIdx.x << 4; // first batch row of this block (16 rows)

    // ---- Theta -> resident B-frags. State part (ks<8) gathered through the
    // sigma permutation T(p) = 16*(p&15) + (p>>4) so that k-slot p matches the
    // state LDS position p (which holds column T(p)). Token part (ks=8,9)
    // unpermuted. B-frag: lane&15 = n, k = ks*32 + q*8 + j.
    bf16x8 bfrag[10][4];
#pragma unroll
    for (int s = 0; s < 4; ++s) {
        const float* trow = theta + (size_t)(w * 64 + s * 16 + loc) * 320;
#pragma unroll
        for (int ks = 0; ks < 8; ++ks) {
            float v[8];
#pragma unroll
            for (int j = 0; j < 8; ++j) {
                int p = ks * 32 + q * 8 + j;
                int c = ((p & 15) << 4) | (p >> 4);   // T(p)
                v[j] = trow[c];
            }
            union { unsigned int u[4]; bf16x8 b; } r;
            r.u[0] = cvtpk(v[0], v[1]); r.u[1] = cvtpk(v[2], v[3]);
            r.u[2] = cvtpk(v[4], v[5]); r.u[3] = cvtpk(v[6], v[7]);
            bfrag[ks][s] = r.b;
        }
#pragma unroll
        for (int ks = 8; ks < 10; ++ks) {
            float4 f0 = *(const float4*)(trow + 256 + (ks - 8) * 32 + q * 8);
            float4 f1 = *(const float4*)(trow + 256 + (ks - 8) * 32 + q * 8 + 4);
            bfrag[ks][s] = pack8(f0, f1);
        }
    }

    // ---- init: raw z(0) = 0; stats of z(0): sum=0, ssq=255 -> var=1, rstd=1,
    // b=0 -> A_norm = relu(0*1+0) = 0, matching zero initial state.
    {
        const int m = tid >> 4, c = (tid & 15) * 16;
        uint4 z = make_uint4(0u, 0u, 0u, 0u);
        *(uint4*)(&stbuf[0][m][c])     = z;
        *(uint4*)(&stbuf[0][m][c + 8]) = z;
    }
    if (tid < 64)
        partials[0][tid >> 2][tid & 3] = make_float2(0.0f, (tid & 3) == 0 ? 255.0f : 0.0f);

    // ---- prefetch token t=0 in A-frag layout: lane = row loc, features q*8..
    const float* srow = seq + (size_t)(r0 + loc) * (TT * VV);
    float4 tk0 = *(const float4*)(srow + q * 8);
    float4 tk1 = *(const float4*)(srow + q * 8 + 4);
    float4 tk2 = *(const float4*)(srow + 32 + q * 8);
    float4 tk3 = *(const float4*)(srow + 32 + q * 8 + 4);

    __syncthreads();

#pragma unroll 1
    for (int t = 0; t < TT; ++t) {
        const unsigned short* stc = &stbuf[t & 1][0][0];
        unsigned short*       stn = &stbuf[(t + 1) & 1][0][0];
        const int pb = t & 1;

        // ---- lane-local stats of z(t) for row loc (4 q-dup lanes redundant) ----
        float4 qa = *(const float4*)(&partials[pb][loc][0]);
        float4 qb = *(const float4*)(&partials[pb][loc][2]);

        // ---- token part -> accumulator init (fills partials-read latency) ----
        bf16x8 a8 = pack8(tk0, tk1);
        bf16x8 a9 = pack8(tk2, tk3);
        f32x4 acc[4];
        {
            f32x4 zc; zc[0] = 0.f; zc[1] = 0.f; zc[2] = 0.f; zc[3] = 0.f;
#pragma unroll
            for (int s = 0; s < 4; ++s) {
                acc[s] = __builtin_amdgcn_mfma_f32_16x16x32_bf16(a8, bfrag[8][s], zc, 0, 0, 0);
                acc[s] = __builtin_amdgcn_mfma_f32_16x16x32_bf16(a9, bfrag[9][s], acc[s], 0, 0, 0);
            }
        }

        // prefetch next step's token (stays in flight across the barrier)
        if (t + 1 < TT) {
            const float* p = srow + (size_t)(t + 1) * VV;
            tk0 = *(const float4*)(p + q * 8);
            tk1 = *(const float4*)(p + q * 8 + 4);
            tk2 = *(const float4*)(p + 32 + q * 8);
            tk3 = *(const float4*)(p + 32 + q * 8 + 4);
        }

        // ---- issue all raw A-frag reads early ----
        uint4 rawf[8];
        const unsigned short* arow = stc + loc * STRD;
#pragma unroll
        for (int ks = 0; ks < 8; ++ks)
            rawf[ks] = *(const uint4*)(arow + ks * 32 + q * 8);

        // ---- finalize stats (lane-local; no broadcasts) ----
        float sumT = (qa.x + qa.z) + (qb.x + qb.z);
        float ssqT = (qa.y + qa.w) + (qb.y + qb.w);
        float mean = sumT * (1.0f / 256.0f);
        float var  = (ssqT - sumT * mean) * (1.0f / 255.0f);   // ddof=1
        float a_   = rsqrtf(var);
        float b_   = -mean * a_;

        // ---- GEMM state part with on-the-fly normalize ----
#pragma unroll
        for (int ks = 0; ks < 8; ++ks) {
            bf16x8 av = normfrag((const unsigned int*)&rawf[ks], a_, b_);
#pragma unroll
            for (int s = 0; s < 4; ++s)
                acc[s] = __builtin_amdgcn_mfma_f32_16x16x32_bf16(av, bfrag[ks][s], acc[s], 0, 0, 0);
        }

        // ---- stats of z(t+1): per-row sums over this wave's 64 columns ----
        // C layout: acc[s][r] is row q*4+r, col w*64 + s*16 + loc
        float sum[4], ssq[4];
#pragma unroll
        for (int r = 0; r < 4; ++r) {
            sum[r] = acc[0][r] + acc[1][r] + acc[2][r] + acc[3][r];
            ssq[r] = acc[0][r] * acc[0][r] + acc[1][r] * acc[1][r]
                   + acc[2][r] * acc[2][r] + acc[3][r] * acc[3][r];
        }
#pragma unroll
        for (int r = 0; r < 4; ++r) {
            sum[r] = dppadd<0xB1>(sum[r]);  ssq[r] = dppadd<0xB1>(ssq[r]);   // quad_perm 1,0,3,2
            sum[r] = dppadd<0x4E>(sum[r]);  ssq[r] = dppadd<0x4E>(ssq[r]);   // quad_perm 2,3,0,1
            sum[r] = dppadd<0x124>(sum[r]); ssq[r] = dppadd<0x124>(ssq[r]);  // row_ror:4
            sum[r] = dppadd<0x128>(sum[r]); ssq[r] = dppadd<0x128>(ssq[r]);  // row_ror:8
        }
        if (loc < 4)
            partials[pb ^ 1][(q << 2) | loc][w] = make_float2(sum[loc], ssq[loc]);

        // ---- write RAW z(t+1), sigma-permuted: col w*64+s*16+loc -> position
        // loc*16 + w*4 + s (s contiguous) -> one b64 per output row ----
        {
            unsigned short* wb = stn + (q * 4) * STRD + loc * 16 + w * 4;
#pragma unroll
            for (int r = 0; r < 4; ++r) {
                uint2 pk;
                pk.x = cvtpk(acc[0][r], acc[1][r]);
                pk.y = cvtpk(acc[2][r], acc[3][r]);
                *(uint2*)(wb + r * STRD) = pk;
            }
        }

        barrier_lgkm();
    }

    // ---- readout: state(512) = relu(z*rstd - mean*rstd) from raw buf[0],
    // stats in partials[0]; theta_dot indexed through T(p) ----
    {
        const int m = tid >> 4, j16 = tid & 15;
        float4 qa = *(const float4*)(&partials[0][m][0]);
        float4 qb = *(const float4*)(&partials[0][m][2]);
        float sumT = (qa.x + qa.z) + (qb.x + qb.z);
        float ssqT = (qa.y + qa.w) + (qb.y + qb.w);
        float mean = sumT * (1.0f / 256.0f);
        float var  = (ssqT - sumT * mean) * (1.0f / 255.0f);
        float a_   = rsqrtf(var);
        float b_   = -mean * a_;

        const unsigned short* sr = &stbuf[0][m][j16 * 16];
        float dot = 0.0f;
#pragma unroll
        for (int j = 0; j < 16; ++j) {
            float v = fmaxf(fmaf(bf2f(sr[j]), a_, b_), 0.0f);
            dot += v * theta_dot[j * 16 + j16];   // position j16*16+j holds col 16j+j16
        }
        dot += __shfl_xor(dot, 1, 64);
        dot += __shfl_xor(dot, 2, 64);
        dot += __shfl_xor(dot, 4, 64);
        dot += __shfl_xor(dot, 8, 64);
        if (j16 == 0)
            out[r0 + m] = 1.0f / (1.0f + expf(-dot));
    }
}

extern "C" void kernel_launch(void* const* d_in, const int* in_sizes, int n_in,
                              void* d_out, int out_size, void* d_ws, size_t ws_size,
                              hipStream_t stream) {
    const float* seq   = (const float*)d_in[0];  // [2048*512*64]
    const float* theta = (const float*)d_in[1];  // [256*320]
    // d_in[2] = bias[1]: constant shift cancels in LayerNorm -> unused
    const float* tdot  = (const float*)d_in[3];  // [256]
    float* out = (float*)d_out;

    rnn_scan_kernel<<<dim3(128), dim3(256), 0, stream>>>(seq, theta, tdot, out);
}